// Round 5
// baseline (595.012 us; speedup 1.0000x reference)
//
#include <hip/hip_runtime.h>
#include <hip/hip_bf16.h>
#include <cstdint>

// ---------- types ----------
typedef __bf16 bf16x8 __attribute__((ext_vector_type(8)));
typedef float  f32x4  __attribute__((ext_vector_type(4)));
typedef float  f32x16 __attribute__((ext_vector_type(16)));

typedef __attribute__((address_space(3))) void lds_void;
typedef const __attribute__((address_space(1))) void gbl_cvoid;

#define GLOAD_LDS16(g, l) \
    __builtin_amdgcn_global_load_lds((gbl_cvoid*)(g), (lds_void*)(l), 16, 0, 0)

// Problem constants
static constexpr int IN   = 4096;
static constexpr int OUT  = 4096;
static constexpr int RANK = 256;
static constexpr int M_ROWS = 4 * 2048;  // B*S = 8192

// ---------- device helpers ----------
__device__ __forceinline__ void cast8(const float* __restrict__ in,
                                      __bf16* __restrict__ out, int t) {
    const float4* p = (const float4*)in + (size_t)t * 2;
    float4 v0 = p[0], v1 = p[1];
    bf16x8 o;
    o[0] = (__bf16)v0.x; o[1] = (__bf16)v0.y; o[2] = (__bf16)v0.z; o[3] = (__bf16)v0.w;
    o[4] = (__bf16)v1.x; o[5] = (__bf16)v1.y; o[6] = (__bf16)v1.z; o[7] = (__bf16)v1.w;
    ((bf16x8*)out)[t] = o;
}

// ---------- kernel 1: prep = cast B (blocks 0..511) + make AdT (blocks 512..767) ----
__global__ __launch_bounds__(256) void prep(
    const float* __restrict__ Bm, __bf16* __restrict__ Bbf,
    const float* __restrict__ A,  const float* __restrict__ d,
    __bf16* __restrict__ AdT)
{
    __shared__ float tile[64][65];
    const int blk = blockIdx.x;
    const int t   = threadIdx.x;

    if (blk < 512) {                     // cast B: 1,048,576 elems / 8
        cast8(Bm, Bbf, blk * 256 + t);
        return;
    }
    const int ab = blk - 512;            // 0..255
    const int i0 = (ab & 63) * 64;
    const int r0 = (ab >> 6) * 64;
    const int cl = t & 63;
    const int rw = t >> 6;

#pragma unroll
    for (int it = 0; it < 16; ++it) {
        int rl = it * 4 + rw;
        tile[rl][cl] = A[(size_t)(r0 + rl) * IN + i0 + cl];
    }
    __syncthreads();
    float dv = d[r0 + cl];
#pragma unroll
    for (int it = 0; it < 16; ++it) {
        int il = it * 4 + rw;
        AdT[(size_t)(i0 + il) * RANK + r0 + cl] = (__bf16)(tile[cl][il] * dv);
    }
}

// ---------- kernel 2a: x cast (grid-stride) ----------
__global__ __launch_bounds__(256) void castx(
    const float* __restrict__ x, __bf16* __restrict__ x_bf)
{
    for (int i = blockIdx.x * 256 + threadIdx.x; i < 4194304; i += 2048 * 256)
        cast8(x, x_bf, i);
}

// ---------- kernel 2b: Weff GEMM ----------
// Weff[o][i] = bf16( W[o][i] + sum_r Bw[o][r]*AdT[i][r] )  (128x128 tile, verified)
__global__ __launch_bounds__(256) void weff(
    const __bf16* __restrict__ Bw,   // [OUT, RANK] bf16
    const __bf16* __restrict__ AdT,  // [IN,  RANK] bf16
    const float*  __restrict__ W,    // [OUT, IN] fp32
    __bf16* __restrict__ Weff)       // [OUT, IN] bf16
{
    __shared__ __bf16 sA[128 * 64];
    __shared__ __bf16 sB[128 * 64];

    const int blk = blockIdx.x;
    const int t   = threadIdx.x;

    constexpr int K = RANK;   // 256
    const int wave = t >> 6;
    const int lane = t & 63;
    const int quad = lane >> 4;
    const int l16  = lane & 15;
    const int m0 = (blk >> 5) * 128;   // o
    const int n0 = (blk & 31) * 128;   // i
    const int wm = (wave >> 1) * 64;
    const int wn = (wave & 1) * 64;
    const int xr = l16 & 7;

    f32x4 acc[4][4] = {};

    for (int kt = 0; kt < K; kt += 64) {
#pragma unroll
        for (int j = 0; j < 4; ++j) {
            int ci  = j * 256 + t;
            int row = ci >> 3;
            int kc  = (ci & 7) ^ (row & 7);
            GLOAD_LDS16(Bw  + (size_t)(m0 + row) * K + kt + kc * 8, sA + ci * 8);
        }
#pragma unroll
        for (int j = 0; j < 4; ++j) {
            int ci  = j * 256 + t;
            int row = ci >> 3;
            int kc  = (ci & 7) ^ (row & 7);
            GLOAD_LDS16(AdT + (size_t)(n0 + row) * K + kt + kc * 8, sB + ci * 8);
        }
        __syncthreads();

#pragma unroll
        for (int kk = 0; kk < 64; kk += 32) {
            const int kb = kk >> 3;
            bf16x8 a[4], b[4];
#pragma unroll
            for (int mi = 0; mi < 4; ++mi)
                a[mi] = *(const bf16x8*)(sA + (wm + mi * 16 + l16) * 64 + (((kb + quad) ^ xr) << 3));
#pragma unroll
            for (int ni = 0; ni < 4; ++ni)
                b[ni] = *(const bf16x8*)(sB + (wn + ni * 16 + l16) * 64 + (((kb + quad) ^ xr) << 3));
#pragma unroll
            for (int mi = 0; mi < 4; ++mi)
#pragma unroll
                for (int ni = 0; ni < 4; ++ni)
                    acc[mi][ni] = __builtin_amdgcn_mfma_f32_16x16x32_bf16(a[mi], b[ni], acc[mi][ni], 0, 0, 0);
        }
        __syncthreads();
    }

#pragma unroll
    for (int mi = 0; mi < 4; ++mi) {
#pragma unroll
        for (int r = 0; r < 4; ++r) {
            int row = m0 + wm + mi * 16 + quad * 4 + r;
#pragma unroll
            for (int ni = 0; ni < 4; ++ni) {
                int col = n0 + wn + ni * 16 + l16;
                size_t idx = (size_t)row * IN + col;
                Weff[idx] = (__bf16)(acc[mi][ni][r] + W[idx]);
            }
        }
    }
}

// ---------- kernel 3: out[m][n] = sum_k X[m][k]*Weff[n][k] + bias[n] ----------
// R5 restructure: FAT-WAVE 32x32 MFMA, 4 waves (2x2), per-wave 128x128 output.
//   R1-R4 bracket 41-46%: per-tile time = LDS-pipe + MFMA-pipe SUMMED, and the
//   8-wave 128x64 decomposition needs 96 KB LDS reads per 32 KB tile (>= MFMA
//   time, so even perfect overlap caps ~56%). Fat waves halve reads/MFMA:
//   4 waves x 16 b128 = 64 KB/tile (~640-900 cyc) < MFMA 32x32x16 pipe
//   (32/wave/tile, ~1034 cyc/SIMD) -> MFMA-bound when overlapped.
//   1 wave/SIMD: overlap via in-order ILP, not wave de-phasing -- per tile:
//     VM(8); barrier; sched_barrier(0);
//     read 8 frags (tile t+1, ks=0) ; stage tile t+3 (8 gloads)
//     16 MFMA (tile t, ks=0)          // reads+stages drain underneath
//     read 8 frags (tile t+1, ks=1)
//     16 MFMA (tile t, ks=1)
//   Ledger (8 gloads/thread/tile): at tile top outstanding = {t+1,t+2} = 16;
//   VM(8) certifies t+1 (whose frags are read this tile). Stage into buf t+3
//   overwrites t-1, whose reads drained before t-1's MFMAs (lgkm) -> before
//   this barrier. Epilogue VM(8),VM(8),VM(0). Prologue VM(16) (24 outstanding)
//   certifies tile 0 and drains prior tp's C-stores (in-order vmcnt).
//   Frag layout 32x32x16: A lane l -> row l&31, k-octet l>>5 (generalizes the
//   verified 16x16x32 pattern); C/D: col=lane&31, row=(reg&3)+8*(reg>>2)+
//   4*(lane>>5) [m74/m101]. Swizzle: chunk c of row r at slot c^((r>>1)&3),
//   16B granularity; read-side bank audit = 2 lanes/bank (free).
//   acc 256 + frag ping-pong 128 VGPR -> ~410, 1 wave/SIMD (256,1 bounds).

#define LDA(BUF, mi, SO) (*(const bf16x8*)&sX[BUF][arow + (mi) * 1024 + (SO)])
#define LDB(BUF, ni, SO) (*(const bf16x8*)&sW[BUF][brow + (ni) * 1024 + (SO)])
#define BARR() __builtin_amdgcn_s_barrier()
#define VM(N)  asm volatile("s_waitcnt vmcnt(" #N ")")

#define STG_X(BUF, P) do { \
    GLOAD_LDS16((P),                  &sX[BUF][tid * 8]); \
    GLOAD_LDS16((P) + (size_t)262144, &sX[BUF][2048 + tid * 8]); \
    GLOAD_LDS16((P) + (size_t)524288, &sX[BUF][4096 + tid * 8]); \
    GLOAD_LDS16((P) + (size_t)786432, &sX[BUF][6144 + tid * 8]); \
} while (0)
#define STG_W(BUF, P) do { \
    GLOAD_LDS16((P),                  &sW[BUF][tid * 8]); \
    GLOAD_LDS16((P) + (size_t)262144, &sW[BUF][2048 + tid * 8]); \
    GLOAD_LDS16((P) + (size_t)524288, &sW[BUF][4096 + tid * 8]); \
    GLOAD_LDS16((P) + (size_t)786432, &sW[BUF][6144 + tid * 8]); \
} while (0)

#define MF(A, B, mi, ni) \
    acc[mi][ni] = __builtin_amdgcn_mfma_f32_32x32x16_bf16(A, B, acc[mi][ni], 0, 0, 0);

#define MHALF(A0, A1, A2, A3, B0, B1, B2, B3) \
    MF(A0, B0, 0, 0) MF(A0, B1, 0, 1) MF(A0, B2, 0, 2) MF(A0, B3, 0, 3) \
    MF(A1, B0, 1, 0) MF(A1, B1, 1, 1) MF(A1, B2, 1, 2) MF(A1, B3, 1, 3) \
    MF(A2, B0, 2, 0) MF(A2, B1, 2, 1) MF(A2, B2, 2, 2) MF(A2, B3, 2, 3) \
    MF(A3, B0, 3, 0) MF(A3, B1, 3, 1) MF(A3, B2, 3, 2) MF(A3, B3, 3, 3)

#define RD8(RBUF, SO, A0, A1, A2, A3, B0, B1, B2, B3) \
    A0 = LDA(RBUF, 0, SO); A1 = LDA(RBUF, 1, SO); \
    A2 = LDA(RBUF, 2, SO); A3 = LDA(RBUF, 3, SO); \
    B0 = LDB(RBUF, 0, SO); B1 = LDB(RBUF, 1, SO); \
    B2 = LDB(RBUF, 2, SO); B3 = LDB(RBUF, 3, SO);

// one K-tile: consume set C (tile t), read set Nn (tile t+1 from RBUF), stage t+3
#define TILE(RBUF, STGS, VMS, C, Nn) \
    { \
        VMS; \
        BARR(); \
        __builtin_amdgcn_sched_barrier(0); \
        RD8(RBUF, s0, Nn##a0, Nn##a1, Nn##a2, Nn##a3, Nn##b0, Nn##b1, Nn##b2, Nn##b3) \
        STGS; \
        __builtin_amdgcn_s_setprio(1); \
        MHALF(C##a0, C##a1, C##a2, C##a3, C##b0, C##b1, C##b2, C##b3) \
        __builtin_amdgcn_s_setprio(0); \
        RD8(RBUF, s1, Nn##a4, Nn##a5, Nn##a6, Nn##a7, Nn##b4, Nn##b5, Nn##b6, Nn##b7) \
        __builtin_amdgcn_s_setprio(1); \
        MHALF(C##a4, C##a5, C##a6, C##a7, C##b4, C##b5, C##b6, C##b7) \
        __builtin_amdgcn_s_setprio(0); \
    }

__global__ __launch_bounds__(256, 1) void main_gemm(
    const __bf16* __restrict__ X,     // [8192, 4096] bf16
    const __bf16* __restrict__ Wf,    // [4096, 4096] bf16
    const float*  __restrict__ bias,  // [4096]
    float* __restrict__ out)          // [8192, 4096] fp32
{
    constexpr int K = IN;     // 4096
    constexpr int N = OUT;    // 4096
    __shared__ __bf16 sX[4][8192];    // 4 bufs x 256 rows x 32 k  (64 KiB)
    __shared__ __bf16 sW[4][8192];    // 4 bufs x 256 rows x 32 k  (64 KiB)

    const int tid  = threadIdx.x;     // 256 threads = 4 waves
    const int lane = tid & 63;
    const int r31  = lane & 31;
    const int h    = lane >> 5;       // k-octet half
    const int wave = tid >> 6;        // 0..3, grid 2Mx2N
    const int wmb  = (wave >> 1) * 128;
    const int wnb  = (wave & 1) * 128;

    // XCD-aware persistent-block decode (bijective: blk = c | (i<<3))
    const int blk    = blockIdx.x;    // 0..255, HW: XCD = blk & 7
    const int c      = blk & 7;
    const int i      = blk >> 3;      // 0..31
    const int n0     = (c * 2 + (i & 1)) * 256;
    const int m_base = (i >> 1) * 256;

    // fragment read addressing (32x32x16: row = r31, k-octet = h; chunk = 2*ks+h)
    const int sz   = (r31 >> 1) & 3;
    const int s0   = ((h ^ sz)) * 8;          // ks=0 slot offset (bf16 units)
    const int s1   = (((2 + h) ^ sz)) * 8;    // ks=1
    const int arow = (wmb + r31) * 32;
    const int brow = (wnb + r31) * 32;

    // stage addressing: linear LDS dst, pre-swizzled global source chunk
    const int row0 = tid >> 2;                       // 0..63 (j adds 64)
    const int ch0  = (tid & 3) ^ ((row0 >> 1) & 3);  // swz bits invariant in j
    const __bf16* wsrc = Wf + (size_t)(n0 + row0) * K + ch0 * 8;

    float bv[4];
#pragma unroll
    for (int ni = 0; ni < 4; ++ni)
        bv[ni] = bias[n0 + wnb + ni * 32 + r31];

#pragma unroll 1
    for (int tp = 0; tp < 2; ++tp) {
        const int m0 = m_base + tp * 4096;
        const __bf16* xsrc = X + (size_t)(m0 + row0) * K + ch0 * 8;

        f32x16 acc[4][4] = {};
        bf16x8 pa0, pa1, pa2, pa3, pa4, pa5, pa6, pa7;
        bf16x8 pb0, pb1, pb2, pb3, pb4, pb5, pb6, pb7;
        bf16x8 qa0, qa1, qa2, qa3, qa4, qa5, qa6, qa7;
        bf16x8 qb0, qb1, qb2, qb3, qb4, qb5, qb6, qb7;

        // prologue: stage tiles 0,1,2 (24 loads); VM(16) certifies tile 0 and
        // drains prior tp's C-stores; then fill set p with tile-0 fragments.
        STG_X(0, xsrc);      STG_W(0, wsrc);
        STG_X(1, xsrc + 32); STG_W(1, wsrc + 32);
        STG_X(2, xsrc + 64); STG_W(2, wsrc + 64);
        VM(16);
        BARR();
        RD8(0, s0, pa0, pa1, pa2, pa3, pb0, pb1, pb2, pb3)
        RD8(0, s1, pa4, pa5, pa6, pa7, pb4, pb5, pb6, pb7)

        const __bf16* xs = xsrc + 96;   // next stage = tile 3
        const __bf16* ws = wsrc + 96;

        // main loop: tiles 0..123 (31 iters x 4); reads t+1, stages t+3
#pragma unroll 1
        for (int it = 0; it < 31; ++it) {
            TILE(1, STG_X(3, xs);      STG_W(3, ws),      VM(8), p, q)
            TILE(2, STG_X(0, xs + 32); STG_W(0, ws + 32), VM(8), q, p)
            TILE(3, STG_X(1, xs + 64); STG_W(1, ws + 64), VM(8), p, q)
            TILE(0, STG_X(2, xs + 96); STG_W(2, ws + 96), VM(8), q, p)
            xs += 128; ws += 128;
        }

        // epilogue: tile 124 (stages 127), 125, 126, then 127 (no reads)
        TILE(1, STG_X(3, xs); STG_W(3, ws), VM(8), p, q)
        TILE(2, (void)0,                    VM(8), q, p)
        TILE(3, (void)0,                    VM(0), p, q)
        __builtin_amdgcn_s_setprio(1);
        MHALF(qa0, qa1, qa2, qa3, qb0, qb1, qb2, qb3)
        __builtin_amdgcn_s_setprio(0);
        __builtin_amdgcn_s_setprio(1);
        MHALF(qa4, qa5, qa6, qa7, qb4, qb5, qb6, qb7)
        __builtin_amdgcn_s_setprio(0);

        // C-write, 32x32 layout: col = r31, row = (reg&3) + 8*(reg>>2) + 4*h
#pragma unroll
        for (int mi = 0; mi < 4; ++mi) {
#pragma unroll
            for (int ni = 0; ni < 4; ++ni) {
#pragma unroll
                for (int reg = 0; reg < 16; ++reg) {
                    int row = m0 + wmb + mi * 32 + (reg & 3) + 8 * (reg >> 2) + 4 * h;
                    int col = n0 + wnb + ni * 32 + r31;
                    out[(size_t)row * N + col] = acc[mi][ni][reg] + bv[ni];
                }
            }
        }
    }
}

#undef TILE
#undef RD8
#undef MHALF
#undef MF
#undef STG_X
#undef STG_W
#undef LDA
#undef LDB
#undef BARR
#undef VM

// ---------- launch ----------
extern "C" void kernel_launch(void* const* d_in, const int* in_sizes, int n_in,
                              void* d_out, int out_size, void* d_ws, size_t ws_size,
                              hipStream_t stream) {
    const float* x  = (const float*)d_in[0];   // [8192, 4096]
    const float* W  = (const float*)d_in[1];   // [4096, 4096]
    const float* A  = (const float*)d_in[2];   // [256, 4096]
    const float* Bm = (const float*)d_in[3];   // [4096, 256]
    const float* d  = (const float*)d_in[4];   // [256]
    const float* b  = (const float*)d_in[5];   // [4096]
    float* out = (float*)d_out;

    // workspace layout
    char* ws = (char*)d_ws;
    __bf16* x_bf   = (__bf16*)(ws);                                  // 67,108,864 B
    __bf16* weff_p = (__bf16*)(ws + (size_t)67108864);               // 33,554,432 B
    __bf16* b_bf   = (__bf16*)(ws + (size_t)67108864 + 33554432);    //  2,097,152 B
    __bf16* adt_bf = (__bf16*)(ws + (size_t)67108864 + 33554432 + 2097152); // 2,097,152 B

    // 1) prep: cast B (512 blocks) + AdT transpose (256 blocks)
    prep<<<768, 256, 0, stream>>>(Bm, b_bf, A, d, adt_bf);
    // 2a) Weff GEMM
    weff<<<1024, 256, 0, stream>>>(b_bf, adt_bf, W, weff_p);
    // 2b) cast x (grid-stride)
    castx<<<2048, 256, 0, stream>>>(x, x_bf);
    // 3) out = x_bf @ Weff^T + b   (fat-wave 32x32 MFMA, 4 waves, ILP pipeline)
    main_gemm<<<256, 256, 0, stream>>>(x_bf, weff_p, b, out);
}